// Round 4
// baseline (210.251 us; speedup 1.0000x reference)
//
#include <hip/hip_runtime.h>

// Problem constants (B,C,H,W = 2,64,48,48; nh=8 -> d=8, L=2304)
#define LL   2304
#define CCH  64
#define NHD  8
#define NB   1280   // 5 blocks/CU exactly (capacity 6 by LDS); balanced P2/P3

static constexpr float QSCALE = 0.35355339059327373f;  // 8^-0.5
static constexpr float LOG2E  = 1.4426950408889634f;

typedef _Float16 half2_t  __attribute__((ext_vector_type(2)));
typedef _Float16 half4_t  __attribute__((ext_vector_type(4)));
typedef _Float16 half8_t  __attribute__((ext_vector_type(8)));
typedef float    float16_t __attribute__((ext_vector_type(16)));

__device__ __forceinline__ half2_t pk_f16(float a, float b) {
    return __builtin_bit_cast(half2_t, __builtin_amdgcn_cvt_pkrtz(a, b));
}

// ---------------------------------------------------------------------------
// Barrier flags: relaxed agent-scope atomics (sc-bypass, uncached - fine for
// a handful of words; NEVER for bulk data, see round-3 post-mortem: 20x HBM
// amplification). All counters/flags are MONOTONE - no resets in the hot
// path, robust across graph replays and rocprof passes.
// ---------------------------------------------------------------------------
__device__ __forceinline__ unsigned ld_f(unsigned* p) {
    return __hip_atomic_load(p, __ATOMIC_RELAXED, __HIP_MEMORY_SCOPE_AGENT);
}
__device__ __forceinline__ void st_f(unsigned* p, unsigned v) {
    __hip_atomic_store(p, v, __ATOMIC_RELAXED, __HIP_MEMORY_SCOPE_AGENT);
}
__device__ __forceinline__ unsigned fadd_f(unsigned* p) {
    return __hip_atomic_fetch_add(p, 1u, __ATOMIC_RELAXED, __HIP_MEMORY_SCOPE_AGENT);
}

struct alignas(128) Pad { unsigned v; unsigned pad[31]; };
__device__ Pad      gArrSub[8];     // cumulative arrivals per bid-residue (160/barrier each)
__device__ Pad      gArrMaster;     // cumulative sub-finishers (8/barrier)
__device__ Pad      gAllArr;        // last generation with all NB arrived
__device__ Pad      gFlushDone[8];  // per-XCD: last flushed generation
__device__ Pad      gInvDone[8];    // per-XCD: last invalidated generation
__device__ Pad      gGen;           // global generation: +3 per kernel run
__device__ unsigned gCensus[2][8];  // epoch-parity census slots (flusher election)

// ---------------------------------------------------------------------------
// Leader-per-XCD device barrier. Cache-maintenance ops per barrier: 8 wbl2 +
// 8 inv TOTAL (vs 2*NB in round 2 = the 27us/barrier cost). Correctness:
//  - every cross-phase address has exactly ONE writer; writes are drained to
//    the local XCD L2 by __syncthreads (vmcnt0) before arrival.
//  - per-XCD flusher: agent RELEASE fence (buffer_wbl2 + waitcnt) pushes the
//    whole XCD's dirty lines to the coherence point; master flips gGen only
//    after all populated XCDs flushed; flusher then does agent ACQUIRE fence
//    (buffer_inv) so its XCD's L2 can't serve stale (poison-fill era) lines.
// ---------------------------------------------------------------------------
__device__ __forceinline__ void grid_barrier(unsigned g, int bid, int t,
                                             int xcd, bool flusher)
{
    const unsigned target = g + 1u;
    __syncthreads();                       // all waves drain vmcnt -> L2
    if (t == 0) {
        bool master = false;
        unsigned pop = 0;
        unsigned v = fadd_f(&gArrSub[bid & 7].v);
        if (v == (NB / 8u) * target - 1u) {            // last of this residue
            unsigned m = fadd_f(&gArrMaster.v);
            if (m == 8u * target - 1u) {               // unique global master
                master = true;
                const unsigned ep = g / 3u;            // g = 3*epoch + k
                if ((g % 3u) == 0u)                    // barrier 0: clear next
                    for (int i = 0; i < 8; ++i)        //   epoch's census slot
                        st_f(&gCensus[(ep + 1u) & 1u][i], 0u);
                for (int i = 0; i < 8; ++i)            // populated-XCD mask
                    if (ld_f(&gCensus[ep & 1u][i]) != 0u) pop |= 1u << i;
                asm volatile("s_waitcnt vmcnt(0)" ::: "memory");
                st_f(&gAllArr.v, target);
            }
        }
        if (flusher) {                                 // one block per XCD
            while (ld_f(&gAllArr.v) < target) __builtin_amdgcn_s_sleep(2);
            __builtin_amdgcn_fence(__ATOMIC_RELEASE, "agent");  // wbl2 + wait
            st_f(&gFlushDone[xcd].v, target);
        }
        if (master) {
            for (int i = 0; i < 8; ++i)
                if (pop & (1u << i))
                    while (ld_f(&gFlushDone[i].v) < target)
                        __builtin_amdgcn_s_sleep(1);
            st_f(&gGen.v, target);                     // flip: data globally visible
        }
        if (flusher) {
            while (ld_f(&gGen.v) < target) __builtin_amdgcn_s_sleep(1);
            __builtin_amdgcn_fence(__ATOMIC_ACQUIRE, "agent");  // inv + wait
            st_f(&gInvDone[xcd].v, target);
        } else {
            while (ld_f(&gInvDone[xcd].v) < target) __builtin_amdgcn_s_sleep(8);
        }
    }
    __syncthreads();
}

// v_mfma_f32_32x32x8_f16 lane maps (K=8):
//   A[m = lane&31][k = (lane>>5)*4 + j]   (half4 per lane)
//   B[k = (lane>>5)*4 + j][n = lane&31]
//   C/D: col = lane&31, row = (reg&3) + 8*(reg>>2) + 4*(lane>>5)

// ---------------------------------------------------------------------------
// Single persistent kernel, 4 phases / 3 barriers, CACHED data path (plain
// loads/stores; round-2-verified phase bodies).
//   P1 qkv   (432 units)          -> qout, Qt, Kt, Vt
//   P2 denom (1152 units, <=1/bl) -> V2 = V^T * 256/D
//   P3 av    (1152 units, <=1/bl) -> ot partial slabs
//   P4 out   (144 units)          -> out
// ---------------------------------------------------------------------------
__global__ __launch_bounds__(256, 6) void k_fused(
    const float* __restrict__ x,
    const float* __restrict__ Wq, const float* __restrict__ bq,
    const float* __restrict__ Wk, const float* __restrict__ bk,
    const float* __restrict__ Wv, const float* __restrict__ bv,
    const float* __restrict__ Wo, const float* __restrict__ bo,
    float* __restrict__ qout, float* __restrict__ out,
    _Float16* __restrict__ Qt, _Float16* __restrict__ Kt, _Float16* __restrict__ Vt,
    _Float16* __restrict__ V2, float* __restrict__ ot)
{
    __shared__ __align__(16) char smraw[24576];
    __shared__ unsigned sInfo[2];
    const int t   = threadIdx.x;
    const int bid = blockIdx.x;

    // ---- registration: true XCD id + per-XCD flusher election (census) ----
    if (t == 0) {
        unsigned xcd;
        asm volatile("s_getreg_b32 %0, hwreg(HW_REG_XCC_ID)" : "=s"(xcd));
        xcd &= 7u;
        unsigned g0 = ld_f(&gGen.v);                     // multiple of 3
        unsigned slot = fadd_f(&gCensus[(g0 / 3u) & 1u][xcd]);
        sInfo[0] = g0;
        sInfo[1] = (xcd << 1) | (slot == 0u ? 1u : 0u);
    }
    __syncthreads();
    const unsigned g0  = sInfo[0];
    const int  xcd     = (int)(sInfo[1] >> 1);
    const bool flusher = (sInfo[1] & 1u) != 0u;

    // ======================= Phase 1: q/k/v conv1x1 =======================
    {
        const int u0 = (432 * bid) / NB, u1 = (432 * (bid + 1)) / NB;  // 0..1
        float (*xs)[32]  = (float(*)[32])smraw;            // [64][32] 8KB
        float (*wsm)[64] = (float(*)[64])(smraw + 8192);   // [64][64] 16KB
        for (int u = u0; u < u1; ++u) {
            const int mat = u / 144, rem = u - mat * 144;
            const int b = rem / 72, l0 = (rem % 72) * 32;
            const float* W    = (mat == 0) ? Wq : (mat == 1 ? Wk : Wv);
            const float* bias = (mat == 0) ? bq : (mat == 1 ? bk : bv);
            const float* xb = x + (long)b * CCH * LL;

            #pragma unroll
            for (int p = 0; p < 2; ++p) {
                int flat = (p * 256 + t) * 4;
                int c = flat >> 5, l = flat & 31;
                *(float4*)&xs[c][l] = *(const float4*)&xb[(long)c * LL + l0 + l];
            }
            #pragma unroll
            for (int p = 0; p < 4; ++p) {
                int flat = (p * 256 + t) * 4;
                int c = flat >> 6, l = flat & 63;
                *(float4*)&wsm[c][l] = *(const float4*)&W[flat];
            }
            __syncthreads();

            const int l  = t & 31;
            const int cg = t >> 5;  // head 0..7
            float acc[8];
            #pragma unroll
            for (int j = 0; j < 8; ++j) acc[j] = 0.f;
            for (int cp = 0; cp < 64; ++cp) {
                float xv = xs[cp][l];
                #pragma unroll
                for (int j = 0; j < 8; ++j) acc[j] = fmaf(wsm[cg * 8 + j][cp], xv, acc[j]);
            }
            long row = (long)(b * NHD + cg) * LL + l0 + l;
            if (mat == 0) {
                half8_t pq;
                #pragma unroll
                for (int j = 0; j < 8; ++j) {
                    float qv = (acc[j] + bias[cg * 8 + j]) * QSCALE;
                    qout[((long)b * CCH + cg * 8 + j) * LL + l0 + l] = qv;
                    pq[j] = (_Float16)(qv * LOG2E);
                }
                *(half8_t*)(Qt + row * 8) = pq;
            } else if (mat == 1) {
                half8_t pk;
                #pragma unroll
                for (int j = 0; j < 8; ++j) pk[j] = (_Float16)(acc[j] + bias[cg * 8 + j]);
                *(half8_t*)(Kt + row * 8) = pk;
            } else {
                half8_t pv;
                #pragma unroll
                for (int j = 0; j < 8; ++j) pv[j] = (_Float16)(acc[j] + bias[cg * 8 + j]);
                *(half8_t*)(Vt + row * 8) = pv;
            }
        }
    }
    grid_barrier(g0 + 0u, bid, t, xcd, flusher);

    // ================ Phase 2: D[k] = sum_q 2^(Q'.K), V2 =================
    {
        const int u0 = (1152 * bid) / NB, u1 = (1152 * (bid + 1)) / NB;  // 0..1
        _Float16 (*lQ)[256][4] = (_Float16(*)[256][4])smraw;   // [2][256][4] 4KB
        float (*Dp)[32] = (float(*)[32])(smraw + 4096);        // [4][32]
        float *rDs      = (float*)(smraw + 4608);              // [32]
        const int lane = t & 63, w = t >> 6;
        const int half = lane >> 5, l31 = lane & 31;

        for (int u = u0; u < u1; ++u) {
            const int bh = u / 72, k0 = (u - bh * 72) * 32;
            half4_t kA = *(const half4_t*)(Kt + ((long)bh * LL + k0 + l31) * 8 + half * 4);
            const float4* qbase = (const float4*)(Qt + (long)bh * LL * 8);
            float4 pre = qbase[t];

            float16_t Dacc = {};
            for (int ch = 0; ch < 9; ++ch) {
                __syncthreads();
                *(float2*)&lQ[0][t][0] = make_float2(pre.x, pre.y);   // d 0..3
                *(float2*)&lQ[1][t][0] = make_float2(pre.z, pre.w);   // d 4..7
                __syncthreads();
                if (ch + 1 < 9) pre = qbase[(ch + 1) * 256 + t];
                #pragma unroll
                for (int T = 0; T < 2; ++T) {
                    half4_t qB = *(const half4_t*)&lQ[half][(2 * w + T) * 32 + l31][0];
                    float16_t S = __builtin_amdgcn_mfma_f32_32x32x8f16(kA, qB, (float16_t){}, 0, 0, 0);
                    #pragma unroll
                    for (int r = 0; r < 16; ++r) Dacc[r] += __builtin_amdgcn_exp2f(S[r]);
                }
            }
            #pragma unroll
            for (int r = 0; r < 16; ++r) {
                float v = Dacc[r];
                v += __shfl_xor(v, 1);  v += __shfl_xor(v, 2);  v += __shfl_xor(v, 4);
                v += __shfl_xor(v, 8);  v += __shfl_xor(v, 16);
                Dacc[r] = v;
            }
            if (l31 == 0) {
                #pragma unroll
                for (int r = 0; r < 16; ++r) {
                    int row = (r & 3) + 8 * (r >> 2) + 4 * half;
                    Dp[w][row] = Dacc[r];
                }
            }
            __syncthreads();
            if (t < 32) rDs[t] = 256.0f / (Dp[0][t] + Dp[1][t] + Dp[2][t] + Dp[3][t]);
            __syncthreads();
            {   // V2[bh][c][k0+kk] = V[k0+kk][c] * rDs[kk]
                int kk = t >> 3, c = t & 7;
                float v = (float)Vt[((long)bh * LL + k0 + kk) * 8 + c];
                V2[((long)bh * 8 + c) * LL + k0 + kk] = (_Float16)(v * rDs[kk]);
            }
            __syncthreads();
        }
    }
    grid_barrier(g0 + 1u, bid, t, xcd, flusher);

    // ===================== Phase 3: O' = V2 . 2^(Q'.K) ====================
    {
        const int u0 = (1152 * bid) / NB, u1 = (1152 * (bid + 1)) / NB;  // 0..1
        _Float16 (*lK)[64][4] = (_Float16(*)[64][4])smraw;          // [2][64][4] 1KB
        _Float16 (*lVt)[72]   = (_Float16(*)[72])(smraw + 1024);    // [8][72]
        const int lane = t & 63, w = t >> 6;
        const int half = lane >> 5, l31 = lane & 31;

        for (int u = u0; u < u1; ++u) {
            const int qb = u % 18, rem2 = u / 18;
            const int bh = rem2 & 15, s = rem2 >> 4;
            const int b = bh >> 3, h = bh & 7;
            const int q0 = qb * 128 + w * 32;

            half4_t qB = *(const half4_t*)(Qt + ((long)bh * LL + q0 + l31) * 8 + half * 4);
            const long ks0 = (long)s * 576;
            const float4*    kbase = (const float4*)(Kt + ((long)bh * LL + ks0) * 8);
            const _Float16*  vbase = V2 + (long)bh * 8 * LL + ks0;

            float4 preK, preV;
            if (t < 64) preK = kbase[t];
            else if (t < 128) {
                int c = (t - 64) >> 3, j8 = (t - 64) & 7;
                preV = *(const float4*)(vbase + (long)c * LL + j8 * 8);
            }

            float16_t O = {};
            for (int ch = 0; ch < 9; ++ch) {
                __syncthreads();
                if (t < 64) {
                    *(float2*)&lK[0][t][0] = make_float2(preK.x, preK.y);
                    *(float2*)&lK[1][t][0] = make_float2(preK.z, preK.w);
                } else if (t < 128) {
                    int c = (t - 64) >> 3, j8 = (t - 64) & 7;
                    *(float4*)&lVt[c][j8 * 8] = preV;
                }
                __syncthreads();
                if (ch + 1 < 9) {
                    if (t < 64) preK = kbase[(ch + 1) * 64 + t];
                    else if (t < 128) {
                        int c = (t - 64) >> 3, j8 = (t - 64) & 7;
                        preV = *(const float4*)(vbase + (long)c * LL + (ch + 1) * 64 + j8 * 8);
                    }
                }
                const int cl = l31 & 7;   // lanes 8..31 duplicate c rows
                #pragma unroll
                for (int T = 0; T < 2; ++T) {
                    int kb = T * 32;
                    half4_t kA = *(const half4_t*)&lK[half][kb + l31][0];
                    float16_t S = __builtin_amdgcn_mfma_f32_32x32x8f16(kA, qB, (float16_t){}, 0, 0, 0);
                    #pragma unroll
                    for (int g = 0; g < 4; ++g) {
                        half2_t p0 = pk_f16(__builtin_amdgcn_exp2f(S[4 * g + 0]),
                                            __builtin_amdgcn_exp2f(S[4 * g + 1]));
                        half2_t p1 = pk_f16(__builtin_amdgcn_exp2f(S[4 * g + 2]),
                                            __builtin_amdgcn_exp2f(S[4 * g + 3]));
                        half4_t pB = __builtin_shufflevector(p0, p1, 0, 1, 2, 3);
                        half4_t vA = *(const half4_t*)&lVt[cl][kb + g * 8 + half * 4];
                        O = __builtin_amdgcn_mfma_f32_32x32x8f16(vA, pB, O, 0, 0, 0);
                    }
                }
            }
            // rows c<8 live in regs 0..3: c = r + 4*half; col q = l31
            float* otb = ot + (long)s * (2 * CCH * LL) + ((long)b * CCH + h * 8) * LL;
            #pragma unroll
            for (int r = 0; r < 4; ++r) {
                int c = r + 4 * half;
                otb[(long)c * LL + q0 + l31] = O[r] * (1.0f / 256.0f);
            }
            __syncthreads();
        }
    }
    grid_barrier(g0 + 2u, bid, t, xcd, flusher);

    // ==================== Phase 4: out = Wo.(sum ot) + bo =================
    {
        const int u0 = (144 * bid) / NB, u1 = (144 * (bid + 1)) / NB;  // 0..1
        float (*os)[32]  = (float(*)[32])smraw;
        float (*wsm)[64] = (float(*)[64])(smraw + 8192);
        const long SLAB = 2 * CCH * (long)LL;
        for (int u = u0; u < u1; ++u) {
            const int b = u / 72, l0 = (u % 72) * 32;
            const float* ob = ot + (long)b * CCH * LL;

            #pragma unroll
            for (int p = 0; p < 2; ++p) {
                int flat = (p * 256 + t) * 4;
                int cv = flat >> 5, l = flat & 31;
                long off = (long)cv * LL + l0 + l;
                float4 a = *(const float4*)&ob[off];
                #pragma unroll
                for (int s = 1; s < 4; ++s) {
                    float4 bb = *(const float4*)&ob[s * SLAB + off];
                    a.x += bb.x; a.y += bb.y; a.z += bb.z; a.w += bb.w;
                }
                *(float4*)&os[cv][l] = a;
            }
            #pragma unroll
            for (int p = 0; p < 4; ++p) {
                int flat = (p * 256 + t) * 4;
                int c = flat >> 6, l = flat & 63;
                *(float4*)&wsm[c][l] = *(const float4*)&Wo[flat];
            }
            __syncthreads();

            const int l  = t & 31;
            const int cg = t >> 5;
            float acc[8];
            #pragma unroll
            for (int j = 0; j < 8; ++j) acc[j] = 0.f;
            for (int cv = 0; cv < 64; ++cv) {
                float xv = os[cv][l];
                #pragma unroll
                for (int j = 0; j < 8; ++j) acc[j] = fmaf(wsm[cg * 8 + j][cv], xv, acc[j]);
            }
            #pragma unroll
            for (int j = 0; j < 8; ++j) {
                int co = cg * 8 + j;
                out[((long)b * CCH + co) * LL + l0 + l] = acc[j] + bo[co];
            }
        }
    }
}

// ---------------------------------------------------------------------------
extern "C" void kernel_launch(void* const* d_in, const int* in_sizes, int n_in,
                              void* d_out, int out_size, void* d_ws, size_t ws_size,
                              hipStream_t stream)
{
    const float* x  = (const float*)d_in[0];
    const float* Wq = (const float*)d_in[1];
    const float* bq = (const float*)d_in[2];
    const float* Wk = (const float*)d_in[3];
    const float* bk = (const float*)d_in[4];
    const float* Wv = (const float*)d_in[5];
    const float* bv = (const float*)d_in[6];
    const float* Wo = (const float*)d_in[7];
    const float* bo = (const float*)d_in[8];

    float* out  = (float*)d_out;          // [2][64][2304]
    float* qout = out + 294912;           // second tuple output: scaled q

    // ws: 4 f16 buffers (576KB ea) + 4 f32 ot slabs (4.7MB) = 7.08 MB
    _Float16* Qt = (_Float16*)d_ws;       // [16][2304][8] f16, * log2e*d^-0.5
    _Float16* Kt = Qt + 294912;           // [16][2304][8] f16
    _Float16* Vt = Kt + 294912;           // [16][2304][8] f16 (raw V)
    _Float16* V2 = Vt + 294912;           // [16][8][2304] f16 = V^T * 256/D
    float*    ot = (float*)(V2 + 294912); // [4][2][64][2304] f32 partial slabs

    k_fused<<<dim3(NB), 256, 0, stream>>>(x, Wq, bq, Wk, bk, Wv, bv, Wo, bo,
                                          qout, out, Qt, Kt, Vt, V2, ot);
}

// Round 7
// 127.341 us; speedup vs baseline: 1.6511x; 1.6511x over previous
//
#include <hip/hip_runtime.h>

// Problem constants (B,C,H,W = 2,64,48,48; nh=8 -> d=8, L=2304)
#define LL   2304
#define CCH  64
#define NHD  8

static constexpr float QSCALE = 0.35355339059327373f;  // 8^-0.5
static constexpr float LOG2E  = 1.4426950408889634f;

typedef _Float16 half2_t  __attribute__((ext_vector_type(2)));
typedef _Float16 half4_t  __attribute__((ext_vector_type(4)));
typedef _Float16 half8_t  __attribute__((ext_vector_type(8)));
typedef float    float16_t __attribute__((ext_vector_type(16)));

__device__ __forceinline__ half2_t pk_f16(float a, float b) {
    return __builtin_bit_cast(half2_t, __builtin_amdgcn_cvt_pkrtz(a, b));
}

// v_mfma_f32_32x32x8_f16 lane maps (K=8):
//   A[m = lane&31][k = (lane>>5)*4 + j]   (half4 per lane)
//   B[k = (lane>>5)*4 + j][n = lane&31]
//   C/D: col = lane&31, row = (reg&3) + 8*(reg>>2) + 4*(lane>>5)

// ---------------------------------------------------------------------------
// Kernel 1: q/k/v = conv1x1(x, W*, b*).  Writes scaled q (f32) to qout, and
// Q' (pre-scaled by log2e), K, V as f16 rows [bh][l][8] to workspace.
// mat==0 blocks additionally initialize out tile to bo (k_av_out accumulates
// its contributions via atomicAdd).
// grid (72 ltiles of 32, B, 3 mats), block 256 = 32 l x 8 heads.
// ---------------------------------------------------------------------------
__global__ __launch_bounds__(256) void k_qkv(
    const float* __restrict__ x,
    const float* __restrict__ Wq, const float* __restrict__ bq,
    const float* __restrict__ Wk, const float* __restrict__ bk,
    const float* __restrict__ Wv, const float* __restrict__ bv,
    const float* __restrict__ bo,
    float* __restrict__ qout, float* __restrict__ outp,
    _Float16* __restrict__ Qt, _Float16* __restrict__ Kt, _Float16* __restrict__ Vt)
{
    __shared__ float xs[64][32];
    __shared__ float wsm[64][64];
    const int t   = threadIdx.x;
    const int l0  = blockIdx.x * 32;
    const int b   = blockIdx.y;
    const int mat = blockIdx.z;
    const float* W    = (mat == 0) ? Wq : (mat == 1 ? Wk : Wv);
    const float* bias = (mat == 0) ? bq : (mat == 1 ? bk : bv);
    const float* xb = x + (long)b * CCH * LL;

    if (mat == 0) {
        // init out tile with output bias (atomic accumulation target)
        #pragma unroll
        for (int p = 0; p < 2; ++p) {
            int flat = (p * 256 + t) * 4;       // 2048 floats = 64co x 32l
            int co = flat >> 5, l = flat & 31;
            float bv4 = bo[co];
            float4 vv = make_float4(bv4, bv4, bv4, bv4);
            *(float4*)&outp[((long)b * CCH + co) * LL + l0 + l] = vv;
        }
    }

    #pragma unroll
    for (int p = 0; p < 2; ++p) {
        int flat = (p * 256 + t) * 4;
        int c = flat >> 5, l = flat & 31;
        *(float4*)&xs[c][l] = *(const float4*)&xb[(long)c * LL + l0 + l];
    }
    #pragma unroll
    for (int p = 0; p < 4; ++p) {
        int flat = (p * 256 + t) * 4;
        int c = flat >> 6, l = flat & 63;
        *(float4*)&wsm[c][l] = *(const float4*)&W[flat];
    }
    __syncthreads();

    const int l  = t & 31;
    const int cg = t >> 5;  // head 0..7
    float acc[8];
    #pragma unroll
    for (int j = 0; j < 8; ++j) acc[j] = 0.f;
    for (int cp = 0; cp < 64; ++cp) {
        float xv = xs[cp][l];
        #pragma unroll
        for (int j = 0; j < 8; ++j) acc[j] = fmaf(wsm[cg * 8 + j][cp], xv, acc[j]);
    }
    long row = (long)(b * NHD + cg) * LL + l0 + l;   // [bh][l] row, 8 f16 each
    if (mat == 0) {
        half8_t pq;
        #pragma unroll
        for (int j = 0; j < 8; ++j) {
            float qv = (acc[j] + bias[cg * 8 + j]) * QSCALE;
            qout[((long)b * CCH + cg * 8 + j) * LL + l0 + l] = qv;
            pq[j] = (_Float16)(qv * LOG2E);
        }
        *(half8_t*)(Qt + row * 8) = pq;
    } else if (mat == 1) {
        half8_t pk;
        #pragma unroll
        for (int j = 0; j < 8; ++j) pk[j] = (_Float16)(acc[j] + bias[cg * 8 + j]);
        *(half8_t*)(Kt + row * 8) = pk;
    } else {
        half8_t pv;
        #pragma unroll
        for (int j = 0; j < 8; ++j) pv[j] = (_Float16)(acc[j] + bias[cg * 8 + j]);
        *(half8_t*)(Vt + row * 8) = pv;
    }
}

// ---------------------------------------------------------------------------
// Kernel 2: D[k] = sum_q 2^(Q'[q].K[k]) via MFMA S^T tiles; epilogue writes
// V2[bh][c][k] = V[k][c] * 256/D[k]  (f16, transposed for k_av's A operand).
// grid (72 ktiles of 32, 16 bh), block 256 = 4 waves splitting q.
// ---------------------------------------------------------------------------
__global__ __launch_bounds__(256) void k_denom(
    const _Float16* __restrict__ Qt, const _Float16* __restrict__ Kt,
    const _Float16* __restrict__ Vt, _Float16* __restrict__ V2)
{
    __shared__ _Float16 lQ[2][256][4];   // 4KB: d-half-split Q chunk (256 rows)
    __shared__ float Dp[4][32];
    __shared__ float rDs[32];
    const int t    = threadIdx.x;
    const int bh   = blockIdx.y;
    const int k0   = blockIdx.x * 32;
    const int lane = t & 63, w = t >> 6;
    const int half = lane >> 5, l31 = lane & 31;

    // fixed A operand: K-tile rows k0..k0+31
    half4_t kA = *(const half4_t*)(Kt + ((long)bh * LL + k0 + l31) * 8 + half * 4);

    const float4* qbase = (const float4*)(Qt + (long)bh * LL * 8);  // 16B rows
    float4 pre = qbase[t];

    float16_t Dacc = {};
    for (int ch = 0; ch < 9; ++ch) {
        __syncthreads();
        *(float2*)&lQ[0][t][0] = make_float2(pre.x, pre.y);   // d 0..3
        *(float2*)&lQ[1][t][0] = make_float2(pre.z, pre.w);   // d 4..7
        __syncthreads();
        if (ch + 1 < 9) pre = qbase[(ch + 1) * 256 + t];
        #pragma unroll
        for (int T = 0; T < 2; ++T) {
            half4_t qB = *(const half4_t*)&lQ[half][(2 * w + T) * 32 + l31][0];
            float16_t S = __builtin_amdgcn_mfma_f32_32x32x8f16(kA, qB, (float16_t){}, 0, 0, 0);
            #pragma unroll
            for (int r = 0; r < 16; ++r) Dacc[r] += __builtin_amdgcn_exp2f(S[r]);
        }
    }
    // reduce over q-cols (lanes within each 32-half)
    #pragma unroll
    for (int r = 0; r < 16; ++r) {
        float v = Dacc[r];
        v += __shfl_xor(v, 1);  v += __shfl_xor(v, 2);  v += __shfl_xor(v, 4);
        v += __shfl_xor(v, 8);  v += __shfl_xor(v, 16);
        Dacc[r] = v;
    }
    if (l31 == 0) {
        #pragma unroll
        for (int r = 0; r < 16; ++r) {
            int row = (r & 3) + 8 * (r >> 2) + 4 * half;
            Dp[w][row] = Dacc[r];
        }
    }
    __syncthreads();
    if (t < 32) rDs[t] = 256.0f / (Dp[0][t] + Dp[1][t] + Dp[2][t] + Dp[3][t]);
    __syncthreads();
    {   // V2[bh][c][k0+kk] = V[k0+kk][c] * rDs[kk]
        int kk = t >> 3, c = t & 7;
        float v = (float)Vt[((long)bh * LL + k0 + kk) * 8 + c];
        V2[((long)bh * 8 + c) * LL + k0 + kk] = (_Float16)(v * rDs[kk]);
    }
}

// ---------------------------------------------------------------------------
// Kernel 3: O'[c,q] = sum_k V2[c,k] * 2^(Q'[q].K[k]); S^T C-regs feed PV MFMA
// as B operand quad-by-quad.  Epilogue (fused former k_out): cross-half
// shuffle gives each lane its q-column of all 8 c; apply Wo column-slice
// (transposed in LDS) and atomicAdd 32 coalesced contributions into out
// (pre-initialized to bo by k_qkv).  No ot slab roundtrip.
// grid (18 q-blocks of 128, 16 bh, 4 ksplits), block 256 = 4 waves x 32 q.
// ---------------------------------------------------------------------------
__global__ __launch_bounds__(256, 4) void k_av_out(
    const _Float16* __restrict__ Qt, const _Float16* __restrict__ Kt,
    const _Float16* __restrict__ V2, const float* __restrict__ Wo,
    float* __restrict__ out)
{
    __shared__ _Float16 lK[2][64][4];    // 1KB: d-half-split K chunk (64 rows)
    __shared__ _Float16 lVt[8][72];      // V2 chunk [8c][64k], padded to 72
    __shared__ float WoT[64][68];        // WoT[cv][co] = Wo[co][cv] (16KB+pad)
    const int t    = threadIdx.x;
    const int bh   = blockIdx.y;
    const int s    = blockIdx.z;
    const int b = bh >> 3, h = bh & 7;
    const int lane = t & 63, w = t >> 6;
    const int half = lane >> 5, l31 = lane & 31;
    const int q0   = blockIdx.x * 128 + w * 32;

    // stage Wo transposed once (visible to epilogue via in-loop barriers)
    #pragma unroll
    for (int p = 0; p < 4; ++p) {
        int flat = p * 256 + t;              // float4 slot 0..1023
        int co = flat >> 4, cv4 = flat & 15;
        float4 v = *(const float4*)&Wo[co * 64 + cv4 * 4];
        WoT[cv4 * 4 + 0][co] = v.x; WoT[cv4 * 4 + 1][co] = v.y;
        WoT[cv4 * 4 + 2][co] = v.z; WoT[cv4 * 4 + 3][co] = v.w;
    }

    // fixed B operand: Q-tile cols q0..q0+31
    half4_t qB = *(const half4_t*)(Qt + ((long)bh * LL + q0 + l31) * 8 + half * 4);

    const long ks0 = (long)s * 576;
    const float4*    kbase = (const float4*)(Kt + ((long)bh * LL + ks0) * 8);
    const _Float16*  vbase = V2 + (long)bh * 8 * LL + ks0;

    float4 preK, preV;
    if (t < 64) preK = kbase[t];
    else if (t < 128) {
        int c = (t - 64) >> 3, j8 = (t - 64) & 7;
        preV = *(const float4*)(vbase + (long)c * LL + j8 * 8);
    }

    float16_t O = {};
    for (int ch = 0; ch < 9; ++ch) {
        __syncthreads();
        if (t < 64) {
            *(float2*)&lK[0][t][0] = make_float2(preK.x, preK.y);
            *(float2*)&lK[1][t][0] = make_float2(preK.z, preK.w);
        } else if (t < 128) {
            int c = (t - 64) >> 3, j8 = (t - 64) & 7;
            *(float4*)&lVt[c][j8 * 8] = preV;
        }
        __syncthreads();
        if (ch + 1 < 9) {
            if (t < 64) preK = kbase[(ch + 1) * 64 + t];
            else if (t < 128) {
                int c = (t - 64) >> 3, j8 = (t - 64) & 7;
                preV = *(const float4*)(vbase + (long)c * LL + (ch + 1) * 64 + j8 * 8);
            }
        }
        const int cl = l31 & 7;   // lanes 8..31 duplicate c rows (D rows >=8 unused)
        #pragma unroll
        for (int T = 0; T < 2; ++T) {
            int kb = T * 32;
            half4_t kA = *(const half4_t*)&lK[half][kb + l31][0];
            float16_t S = __builtin_amdgcn_mfma_f32_32x32x8f16(kA, qB, (float16_t){}, 0, 0, 0);
            #pragma unroll
            for (int g = 0; g < 4; ++g) {
                half2_t p0 = pk_f16(__builtin_amdgcn_exp2f(S[4 * g + 0]),
                                    __builtin_amdgcn_exp2f(S[4 * g + 1]));
                half2_t p1 = pk_f16(__builtin_amdgcn_exp2f(S[4 * g + 2]),
                                    __builtin_amdgcn_exp2f(S[4 * g + 3]));
                half4_t pB = __builtin_shufflevector(p0, p1, 0, 1, 2, 3);
                half4_t vA = *(const half4_t*)&lVt[cl][kb + g * 8 + half * 4];
                O = __builtin_amdgcn_mfma_f32_32x32x8f16(vA, pB, O, 0, 0, 0);
            }
        }
    }

    // ---- fused k_out epilogue ----
    // O rows c<8 in regs 0..3: c = r + 4*half, col q = l31.  Swap halves so
    // every lane holds all 8 c for its q (static indices: rule-of-scratch).
    float ocl[4], och[4];
    #pragma unroll
    for (int r = 0; r < 4; ++r) {
        float mine  = O[r] * (1.0f / 256.0f);
        float other = __shfl_xor(mine, 32);
        ocl[r] = half ? other : mine;    // c = r
        och[r] = half ? mine  : other;   // c = 4 + r
    }
    // half 0 covers co 0..31, half 1 covers co 32..63; lanes = consecutive q
    // -> each atomic instr is two coalesced 128B segments.
    float* ob = out + ((long)b * CCH) * LL + q0 + l31;
    #pragma unroll
    for (int g = 0; g < 2; ++g) {
        const int co0 = half * 32 + g * 16;
        float acc2[16];
        #pragma unroll
        for (int j = 0; j < 16; ++j) acc2[j] = 0.f;
        #pragma unroll
        for (int c = 0; c < 8; ++c) {
            float ov = (c < 4) ? ocl[c] : och[c - 4];   // compile-time select
            #pragma unroll
            for (int j4 = 0; j4 < 4; ++j4) {
                const float4 wv = *(const float4*)&WoT[h * 8 + c][co0 + j4 * 4];
                acc2[j4 * 4 + 0] = fmaf(wv.x, ov, acc2[j4 * 4 + 0]);
                acc2[j4 * 4 + 1] = fmaf(wv.y, ov, acc2[j4 * 4 + 1]);
                acc2[j4 * 4 + 2] = fmaf(wv.z, ov, acc2[j4 * 4 + 2]);
                acc2[j4 * 4 + 3] = fmaf(wv.w, ov, acc2[j4 * 4 + 3]);
            }
        }
        #pragma unroll
        for (int j = 0; j < 16; ++j)
            atomicAdd(ob + (long)(co0 + j) * LL, acc2[j]);
    }
}

// ---------------------------------------------------------------------------
extern "C" void kernel_launch(void* const* d_in, const int* in_sizes, int n_in,
                              void* d_out, int out_size, void* d_ws, size_t ws_size,
                              hipStream_t stream)
{
    const float* x  = (const float*)d_in[0];
    const float* Wq = (const float*)d_in[1];
    const float* bq = (const float*)d_in[2];
    const float* Wk = (const float*)d_in[3];
    const float* bk = (const float*)d_in[4];
    const float* Wv = (const float*)d_in[5];
    const float* bv = (const float*)d_in[6];
    const float* Wo = (const float*)d_in[7];
    const float* bo = (const float*)d_in[8];

    float* out  = (float*)d_out;          // [2][64][2304]
    float* qout = out + 294912;           // second tuple output: scaled q

    // ws: 4 f16 buffers (576KB ea) = 2.25 MB (ot slab eliminated)
    _Float16* Qt = (_Float16*)d_ws;       // [16][2304][8] f16, * log2e*d^-0.5
    _Float16* Kt = Qt + 294912;           // [16][2304][8] f16
    _Float16* Vt = Kt + 294912;           // [16][2304][8] f16 (raw V)
    _Float16* V2 = Vt + 294912;           // [16][8][2304] f16 = V^T * 256/D

    k_qkv   <<<dim3(72, 2, 3),  256, 0, stream>>>(x, Wq, bq, Wk, bk, Wv, bv, bo,
                                                  qout, out, Qt, Kt, Vt);
    k_denom <<<dim3(72, 16),    256, 0, stream>>>(Qt, Kt, Vt, V2);
    k_av_out<<<dim3(18, 16, 4), 256, 0, stream>>>(Qt, Kt, V2, Wo, out);
}

// Round 8
// 116.516 us; speedup vs baseline: 1.8045x; 1.0929x over previous
//
#include <hip/hip_runtime.h>

// Problem constants (B,C,H,W = 2,64,48,48; nh=8 -> d=8, L=2304)
#define LL   2304
#define CCH  64
#define NHD  8

static constexpr float QSCALE = 0.35355339059327373f;  // 8^-0.5
static constexpr float LOG2E  = 1.4426950408889634f;

typedef _Float16 half2_t  __attribute__((ext_vector_type(2)));
typedef _Float16 half4_t  __attribute__((ext_vector_type(4)));
typedef _Float16 half8_t  __attribute__((ext_vector_type(8)));
typedef float    float16_t __attribute__((ext_vector_type(16)));

__device__ __forceinline__ half2_t pk_f16(float a, float b) {
    return __builtin_bit_cast(half2_t, __builtin_amdgcn_cvt_pkrtz(a, b));
}

// v_mfma_f32_32x32x8_f16 lane maps (K=8):
//   A[m = lane&31][k = (lane>>5)*4 + j]   (half4 per lane)
//   B[k = (lane>>5)*4 + j][n = lane&31]
//   C/D: col = lane&31, row = (reg&3) + 8*(reg>>2) + 4*(lane>>5)

// ---------------------------------------------------------------------------
// Kernel 1: q/k/v = conv1x1(x, W*, b*)  (verified R7).  mat==0 blocks also
// initialize out to bo (atomic accumulation target for k_av_out).
// grid (72 ltiles of 32, B, 3 mats), block 256 = 32 l x 8 heads.
// ---------------------------------------------------------------------------
__global__ __launch_bounds__(256) void k_qkv(
    const float* __restrict__ x,
    const float* __restrict__ Wq, const float* __restrict__ bq,
    const float* __restrict__ Wk, const float* __restrict__ bk,
    const float* __restrict__ Wv, const float* __restrict__ bv,
    const float* __restrict__ bo,
    float* __restrict__ qout, float* __restrict__ outp,
    _Float16* __restrict__ Qt, _Float16* __restrict__ Kt, _Float16* __restrict__ Vt)
{
    __shared__ float xs[64][32];
    __shared__ float wsm[64][64];
    const int t   = threadIdx.x;
    const int l0  = blockIdx.x * 32;
    const int b   = blockIdx.y;
    const int mat = blockIdx.z;
    const float* W    = (mat == 0) ? Wq : (mat == 1 ? Wk : Wv);
    const float* bias = (mat == 0) ? bq : (mat == 1 ? bk : bv);
    const float* xb = x + (long)b * CCH * LL;

    if (mat == 0) {
        #pragma unroll
        for (int p = 0; p < 2; ++p) {
            int flat = (p * 256 + t) * 4;       // 2048 floats = 64co x 32l
            int co = flat >> 5, l = flat & 31;
            float bv4 = bo[co];
            float4 vv = make_float4(bv4, bv4, bv4, bv4);
            *(float4*)&outp[((long)b * CCH + co) * LL + l0 + l] = vv;
        }
    }

    #pragma unroll
    for (int p = 0; p < 2; ++p) {
        int flat = (p * 256 + t) * 4;
        int c = flat >> 5, l = flat & 31;
        *(float4*)&xs[c][l] = *(const float4*)&xb[(long)c * LL + l0 + l];
    }
    #pragma unroll
    for (int p = 0; p < 4; ++p) {
        int flat = (p * 256 + t) * 4;
        int c = flat >> 6, l = flat & 63;
        *(float4*)&wsm[c][l] = *(const float4*)&W[flat];
    }
    __syncthreads();

    const int l  = t & 31;
    const int cg = t >> 5;  // head 0..7
    float acc[8];
    #pragma unroll
    for (int j = 0; j < 8; ++j) acc[j] = 0.f;
    for (int cp = 0; cp < 64; ++cp) {
        float xv = xs[cp][l];
        #pragma unroll
        for (int j = 0; j < 8; ++j) acc[j] = fmaf(wsm[cg * 8 + j][cp], xv, acc[j]);
    }
    long row = (long)(b * NHD + cg) * LL + l0 + l;   // [bh][l] row, 8 f16 each
    if (mat == 0) {
        half8_t pq;
        #pragma unroll
        for (int j = 0; j < 8; ++j) {
            float qv = (acc[j] + bias[cg * 8 + j]) * QSCALE;
            qout[((long)b * CCH + cg * 8 + j) * LL + l0 + l] = qv;
            pq[j] = (_Float16)(qv * LOG2E);
        }
        *(half8_t*)(Qt + row * 8) = pq;
    } else if (mat == 1) {
        half8_t pk;
        #pragma unroll
        for (int j = 0; j < 8; ++j) pk[j] = (_Float16)(acc[j] + bias[cg * 8 + j]);
        *(half8_t*)(Kt + row * 8) = pk;
    } else {
        half8_t pv;
        #pragma unroll
        for (int j = 0; j < 8; ++j) pv[j] = (_Float16)(acc[j] + bias[cg * 8 + j]);
        *(half8_t*)(Vt + row * 8) = pv;
    }
}

// ---------------------------------------------------------------------------
// Kernel 2: D[k] = sum_q 2^(Q'[q].K[k]); V2[bh][c][k] = V[k][c]*256/D[k].
// (verified R0/R7, unchanged)
// grid (72 ktiles of 32, 16 bh), block 256 = 4 waves splitting q.
// ---------------------------------------------------------------------------
__global__ __launch_bounds__(256) void k_denom(
    const _Float16* __restrict__ Qt, const _Float16* __restrict__ Kt,
    const _Float16* __restrict__ Vt, _Float16* __restrict__ V2)
{
    __shared__ _Float16 lQ[2][256][4];   // 4KB: d-half-split Q chunk (256 rows)
    __shared__ float Dp[4][32];
    __shared__ float rDs[32];
    const int t    = threadIdx.x;
    const int bh   = blockIdx.y;
    const int k0   = blockIdx.x * 32;
    const int lane = t & 63, w = t >> 6;
    const int half = lane >> 5, l31 = lane & 31;

    half4_t kA = *(const half4_t*)(Kt + ((long)bh * LL + k0 + l31) * 8 + half * 4);

    const float4* qbase = (const float4*)(Qt + (long)bh * LL * 8);  // 16B rows
    float4 pre = qbase[t];

    float16_t Dacc = {};
    for (int ch = 0; ch < 9; ++ch) {
        __syncthreads();
        *(float2*)&lQ[0][t][0] = make_float2(pre.x, pre.y);   // d 0..3
        *(float2*)&lQ[1][t][0] = make_float2(pre.z, pre.w);   // d 4..7
        __syncthreads();
        if (ch + 1 < 9) pre = qbase[(ch + 1) * 256 + t];
        #pragma unroll
        for (int T = 0; T < 2; ++T) {
            half4_t qB = *(const half4_t*)&lQ[half][(2 * w + T) * 32 + l31][0];
            float16_t S = __builtin_amdgcn_mfma_f32_32x32x8f16(kA, qB, (float16_t){}, 0, 0, 0);
            #pragma unroll
            for (int r = 0; r < 16; ++r) Dacc[r] += __builtin_amdgcn_exp2f(S[r]);
        }
    }
    #pragma unroll
    for (int r = 0; r < 16; ++r) {
        float v = Dacc[r];
        v += __shfl_xor(v, 1);  v += __shfl_xor(v, 2);  v += __shfl_xor(v, 4);
        v += __shfl_xor(v, 8);  v += __shfl_xor(v, 16);
        Dacc[r] = v;
    }
    if (l31 == 0) {
        #pragma unroll
        for (int r = 0; r < 16; ++r) {
            int row = (r & 3) + 8 * (r >> 2) + 4 * half;
            Dp[w][row] = Dacc[r];
        }
    }
    __syncthreads();
    if (t < 32) rDs[t] = 256.0f / (Dp[0][t] + Dp[1][t] + Dp[2][t] + Dp[3][t]);
    __syncthreads();
    {   // V2[bh][c][k0+kk] = V[k0+kk][c] * rDs[kk]
        int kk = t >> 3, c = t & 7;
        float v = (float)Vt[((long)bh * LL + k0 + kk) * 8 + c];
        V2[((long)bh * 8 + c) * LL + k0 + kk] = (_Float16)(v * rDs[kk]);
    }
}

// ---------------------------------------------------------------------------
// Kernel 3 (fused AV + Wo): block = (qtile of 96, b, ksplit of 576) owns ALL
// 8 heads -> full 64-channel O' tile in-block -> apply Wo in-block -> only 4
// producer blocks per out element (the s-splits): 1.18M coalesced atomics
// (R7's 9.4M at 32 producers was the +20us regression).
// grid (24, 2, 4), block 512 = 8 waves; wave w = head w, 3 q-units of 32.
// LDS 115KB -> 1 block/CU.
// ---------------------------------------------------------------------------
__global__ __launch_bounds__(512) void k_av_out(
    const _Float16* __restrict__ Qt, const _Float16* __restrict__ Kt,
    const _Float16* __restrict__ V2, const float* __restrict__ Wo,
    float* __restrict__ out)
{
    __shared__ _Float16 lK[8][2][288][4];   // 36864B: per-head d-half-split K
    __shared__ _Float16 lV[8][8][296];      // 37888B: per-head V2 rows (pad +8)
    __shared__ float    WoT[64][68];        // 17408B: WoT[cv][co] = Wo[co][cv]
    __shared__ float    Os[64][100];        // 25600B: O' [cv][96q] (pad +4)
    const int t    = threadIdx.x;
    const int qb   = blockIdx.x;
    const int b    = blockIdx.y;
    const int s    = blockIdx.z;
    const int lane = t & 63, h = t >> 6;         // wave index == head
    const int half = lane >> 5, l31 = lane & 31;
    const int cl   = l31 & 7;
    const int bh   = b * NHD + h;

    // stage Wo transposed (read only in epilogue, after many barriers)
    #pragma unroll
    for (int p = 0; p < 2; ++p) {
        int flat = p * 512 + t;              // float4 slot 0..1023
        int co = flat >> 4, cv4 = flat & 15;
        float4 v = *(const float4*)&Wo[co * 64 + cv4 * 4];
        WoT[cv4 * 4 + 0][co] = v.x; WoT[cv4 * 4 + 1][co] = v.y;
        WoT[cv4 * 4 + 2][co] = v.z; WoT[cv4 * 4 + 3][co] = v.w;
    }

    // fixed B operands: 3 q-units of 32 cols each
    const long qrow = (long)bh * LL + qb * 96 + l31;
    half4_t qB0 = *(const half4_t*)(Qt + (qrow +  0) * 8 + half * 4);
    half4_t qB1 = *(const half4_t*)(Qt + (qrow + 32) * 8 + half * 4);
    half4_t qB2 = *(const half4_t*)(Qt + (qrow + 64) * 8 + half * 4);

    float16_t O0 = {}, O1 = {}, O2 = {};

    // 9 x 32k inner steps per 288-k half;  Oacc += V2 . 2^(Q'.K)
    #define UNIT_STEP(Oacc, qBu)                                               \
        _Pragma("unroll")                                                      \
        for (int k32 = 0; k32 < 9; ++k32) {                                    \
            const int kb = k32 * 32;                                           \
            half4_t kA = *(const half4_t*)&lK[h][half][kb + l31][0];           \
            float16_t S = __builtin_amdgcn_mfma_f32_32x32x8f16(kA, qBu, (float16_t){}, 0, 0, 0); \
            _Pragma("unroll")                                                  \
            for (int g = 0; g < 4; ++g) {                                      \
                half2_t p0 = pk_f16(__builtin_amdgcn_exp2f(S[4*g+0]),          \
                                    __builtin_amdgcn_exp2f(S[4*g+1]));         \
                half2_t p1 = pk_f16(__builtin_amdgcn_exp2f(S[4*g+2]),          \
                                    __builtin_amdgcn_exp2f(S[4*g+3]));         \
                half4_t pB = __builtin_shufflevector(p0, p1, 0, 1, 2, 3);      \
                half4_t vA = *(const half4_t*)&lV[h][cl][kb + g*8 + half*4];   \
                Oacc = __builtin_amdgcn_mfma_f32_32x32x8f16(vA, pB, Oacc, 0, 0, 0); \
            }                                                                  \
        }

    for (int kh = 0; kh < 2; ++kh) {
        const long ksb = (long)s * 576 + kh * 288;
        __syncthreads();   // prev-half compute done before restaging
        // stage K: 8 heads x 288 rows, one float4 (8 f16 = d0..7) per row
        for (int i = t; i < 2304; i += 512) {
            int hi = i / 288, row = i - hi * 288;
            float4 kv = *(const float4*)&Kt[((long)(b * NHD + hi) * LL + ksb + row) * 8];
            *(float2*)&lK[hi][0][row][0] = make_float2(kv.x, kv.y);
            *(float2*)&lK[hi][1][row][0] = make_float2(kv.z, kv.w);
        }
        // stage V2: 8 heads x 8 c-rows x 288 k = 64 rows x 36 float4
        for (int i = t; i < 2304; i += 512) {
            int r = i / 36, j = i - r * 36;
            int hi = r >> 3, c = r & 7;
            *(float4*)&lV[hi][c][j * 8] =
                *(const float4*)&V2[((long)(b * NHD + hi) * NHD + c) * LL + ksb + j * 8];
        }
        __syncthreads();
        UNIT_STEP(O0, qB0)
        UNIT_STEP(O1, qB1)
        UNIT_STEP(O2, qB2)
    }
    #undef UNIT_STEP

    // stage O' into LDS: rows cv = h*8 + c (c = r + 4*half), cols q-unit*32+l31
    #pragma unroll
    for (int r = 0; r < 4; ++r) {
        const int c = r + 4 * half;
        Os[h * 8 + c][ 0 + l31] = O0[r] * (1.0f / 256.0f);
        Os[h * 8 + c][32 + l31] = O1[r] * (1.0f / 256.0f);
        Os[h * 8 + c][64 + l31] = O2[r] * (1.0f / 256.0f);
    }
    __syncthreads();

    // in-block Wo epilogue: 384 threads = 96 q x 4 co-groups of 16.
    // Lanes span consecutive q -> Os reads contiguous, WoT reads ~uniform,
    // atomics coalesced (64 consecutive floats per wave-instr).
    if (t < 384) {
        const int q   = t % 96;
        const int cog = t / 96;
        float acc[16];
        #pragma unroll
        for (int j = 0; j < 16; ++j) acc[j] = 0.f;
        for (int cv = 0; cv < 64; ++cv) {
            float ov = Os[cv][q];
            #pragma unroll
            for (int j4 = 0; j4 < 4; ++j4) {
                float4 wv = *(const float4*)&WoT[cv][cog * 16 + j4 * 4];
                acc[j4 * 4 + 0] = fmaf(wv.x, ov, acc[j4 * 4 + 0]);
                acc[j4 * 4 + 1] = fmaf(wv.y, ov, acc[j4 * 4 + 1]);
                acc[j4 * 4 + 2] = fmaf(wv.z, ov, acc[j4 * 4 + 2]);
                acc[j4 * 4 + 3] = fmaf(wv.w, ov, acc[j4 * 4 + 3]);
            }
        }
        float* ob = out + ((long)b * CCH + cog * 16) * LL + qb * 96 + q;
        #pragma unroll
        for (int j = 0; j < 16; ++j)
            atomicAdd(ob + (long)j * LL, acc[j]);
    }
}

// ---------------------------------------------------------------------------
extern "C" void kernel_launch(void* const* d_in, const int* in_sizes, int n_in,
                              void* d_out, int out_size, void* d_ws, size_t ws_size,
                              hipStream_t stream)
{
    const float* x  = (const float*)d_in[0];
    const float* Wq = (const float*)d_in[1];
    const float* bq = (const float*)d_in[2];
    const float* Wk = (const float*)d_in[3];
    const float* bk = (const float*)d_in[4];
    const float* Wv = (const float*)d_in[5];
    const float* bv = (const float*)d_in[6];
    const float* Wo = (const float*)d_in[7];
    const float* bo = (const float*)d_in[8];

    float* out  = (float*)d_out;          // [2][64][2304]
    float* qout = out + 294912;           // second tuple output: scaled q

    // ws: 4 f16 buffers (576KB ea) = 2.25 MB
    _Float16* Qt = (_Float16*)d_ws;       // [16][2304][8] f16, * log2e*d^-0.5
    _Float16* Kt = Qt + 294912;           // [16][2304][8] f16
    _Float16* Vt = Kt + 294912;           // [16][2304][8] f16 (raw V)
    _Float16* V2 = Vt + 294912;           // [16][8][2304] f16 = V^T * 256/D

    k_qkv   <<<dim3(72, 2, 3), 256, 0, stream>>>(x, Wq, bq, Wk, bk, Wv, bv, bo,
                                                 qout, out, Qt, Kt, Vt);
    k_denom <<<dim3(72, 16),   256, 0, stream>>>(Qt, Kt, Vt, V2);
    k_av_out<<<dim3(24, 2, 4), 512, 0, stream>>>(Qt, Kt, V2, Wo, out);
}

// Round 9
// 106.516 us; speedup vs baseline: 1.9739x; 1.0939x over previous
//
#include <hip/hip_runtime.h>

// Problem constants (B,C,H,W = 2,64,48,48; nh=8 -> d=8, L=2304)
#define LL   2304
#define CCH  64
#define NHD  8

static constexpr float QSCALE = 0.35355339059327373f;  // 8^-0.5
static constexpr float LOG2E  = 1.4426950408889634f;

typedef _Float16 half2_t  __attribute__((ext_vector_type(2)));
typedef _Float16 half4_t  __attribute__((ext_vector_type(4)));
typedef _Float16 half8_t  __attribute__((ext_vector_type(8)));
typedef float    float16_t __attribute__((ext_vector_type(16)));

__device__ __forceinline__ half2_t pk_f16(float a, float b) {
    return __builtin_bit_cast(half2_t, __builtin_amdgcn_cvt_pkrtz(a, b));
}

// v_mfma_f32_32x32x8_f16 lane maps (K=8):
//   A[m = lane&31][k = (lane>>5)*4 + j]   (half4 per lane)
//   B[k = (lane>>5)*4 + j][n = lane&31]
//   C/D: col = lane&31, row = (reg&3) + 8*(reg>>2) + 4*(lane>>5)

// ---------------------------------------------------------------------------
// Kernel 1: q/k/v = conv1x1(x, W*, b*)  (verified R7/R8).  mat==0 blocks also
// initialize out to bo (atomic accumulation target for k_av_out).
// grid (72 ltiles of 32, B, 3 mats), block 256 = 32 l x 8 heads.
// ---------------------------------------------------------------------------
__global__ __launch_bounds__(256) void k_qkv(
    const float* __restrict__ x,
    const float* __restrict__ Wq, const float* __restrict__ bq,
    const float* __restrict__ Wk, const float* __restrict__ bk,
    const float* __restrict__ Wv, const float* __restrict__ bv,
    const float* __restrict__ bo,
    float* __restrict__ qout, float* __restrict__ outp,
    _Float16* __restrict__ Qt, _Float16* __restrict__ Kt, _Float16* __restrict__ Vt)
{
    __shared__ float xs[64][32];
    __shared__ float wsm[64][64];
    const int t   = threadIdx.x;
    const int l0  = blockIdx.x * 32;
    const int b   = blockIdx.y;
    const int mat = blockIdx.z;
    const float* W    = (mat == 0) ? Wq : (mat == 1 ? Wk : Wv);
    const float* bias = (mat == 0) ? bq : (mat == 1 ? bk : bv);
    const float* xb = x + (long)b * CCH * LL;

    if (mat == 0) {
        #pragma unroll
        for (int p = 0; p < 2; ++p) {
            int flat = (p * 256 + t) * 4;       // 2048 floats = 64co x 32l
            int co = flat >> 5, l = flat & 31;
            float bv4 = bo[co];
            float4 vv = make_float4(bv4, bv4, bv4, bv4);
            *(float4*)&outp[((long)b * CCH + co) * LL + l0 + l] = vv;
        }
    }

    #pragma unroll
    for (int p = 0; p < 2; ++p) {
        int flat = (p * 256 + t) * 4;
        int c = flat >> 5, l = flat & 31;
        *(float4*)&xs[c][l] = *(const float4*)&xb[(long)c * LL + l0 + l];
    }
    #pragma unroll
    for (int p = 0; p < 4; ++p) {
        int flat = (p * 256 + t) * 4;
        int c = flat >> 6, l = flat & 63;
        *(float4*)&wsm[c][l] = *(const float4*)&W[flat];
    }
    __syncthreads();

    const int l  = t & 31;
    const int cg = t >> 5;  // head 0..7
    float acc[8];
    #pragma unroll
    for (int j = 0; j < 8; ++j) acc[j] = 0.f;
    for (int cp = 0; cp < 64; ++cp) {
        float xv = xs[cp][l];
        #pragma unroll
        for (int j = 0; j < 8; ++j) acc[j] = fmaf(wsm[cg * 8 + j][cp], xv, acc[j]);
    }
    long row = (long)(b * NHD + cg) * LL + l0 + l;   // [bh][l] row, 8 f16 each
    if (mat == 0) {
        half8_t pq;
        #pragma unroll
        for (int j = 0; j < 8; ++j) {
            float qv = (acc[j] + bias[cg * 8 + j]) * QSCALE;
            qout[((long)b * CCH + cg * 8 + j) * LL + l0 + l] = qv;
            pq[j] = (_Float16)(qv * LOG2E);
        }
        *(half8_t*)(Qt + row * 8) = pq;
    } else if (mat == 1) {
        half8_t pk;
        #pragma unroll
        for (int j = 0; j < 8; ++j) pk[j] = (_Float16)(acc[j] + bias[cg * 8 + j]);
        *(half8_t*)(Kt + row * 8) = pk;
    } else {
        half8_t pv;
        #pragma unroll
        for (int j = 0; j < 8; ++j) pv[j] = (_Float16)(acc[j] + bias[cg * 8 + j]);
        *(half8_t*)(Vt + row * 8) = pv;
    }
}

// ---------------------------------------------------------------------------
// Kernel 2: D[k] = sum_q 2^(Q'[q].K[k]); V2[bh][c][k] = V[k][c]*256/D[k].
// (verified R0/R7/R8, unchanged)
// grid (72 ktiles of 32, 16 bh), block 256 = 4 waves splitting q.
// ---------------------------------------------------------------------------
__global__ __launch_bounds__(256) void k_denom(
    const _Float16* __restrict__ Qt, const _Float16* __restrict__ Kt,
    const _Float16* __restrict__ Vt, _Float16* __restrict__ V2)
{
    __shared__ _Float16 lQ[2][256][4];   // 4KB: d-half-split Q chunk (256 rows)
    __shared__ float Dp[4][32];
    __shared__ float rDs[32];
    const int t    = threadIdx.x;
    const int bh   = blockIdx.y;
    const int k0   = blockIdx.x * 32;
    const int lane = t & 63, w = t >> 6;
    const int half = lane >> 5, l31 = lane & 31;

    half4_t kA = *(const half4_t*)(Kt + ((long)bh * LL + k0 + l31) * 8 + half * 4);

    const float4* qbase = (const float4*)(Qt + (long)bh * LL * 8);  // 16B rows
    float4 pre = qbase[t];

    float16_t Dacc = {};
    for (int ch = 0; ch < 9; ++ch) {
        __syncthreads();
        *(float2*)&lQ[0][t][0] = make_float2(pre.x, pre.y);   // d 0..3
        *(float2*)&lQ[1][t][0] = make_float2(pre.z, pre.w);   // d 4..7
        __syncthreads();
        if (ch + 1 < 9) pre = qbase[(ch + 1) * 256 + t];
        #pragma unroll
        for (int T = 0; T < 2; ++T) {
            half4_t qB = *(const half4_t*)&lQ[half][(2 * w + T) * 32 + l31][0];
            float16_t S = __builtin_amdgcn_mfma_f32_32x32x8f16(kA, qB, (float16_t){}, 0, 0, 0);
            #pragma unroll
            for (int r = 0; r < 16; ++r) Dacc[r] += __builtin_amdgcn_exp2f(S[r]);
        }
    }
    #pragma unroll
    for (int r = 0; r < 16; ++r) {
        float v = Dacc[r];
        v += __shfl_xor(v, 1);  v += __shfl_xor(v, 2);  v += __shfl_xor(v, 4);
        v += __shfl_xor(v, 8);  v += __shfl_xor(v, 16);
        Dacc[r] = v;
    }
    if (l31 == 0) {
        #pragma unroll
        for (int r = 0; r < 16; ++r) {
            int row = (r & 3) + 8 * (r >> 2) + 4 * half;
            Dp[w][row] = Dacc[r];
        }
    }
    __syncthreads();
    if (t < 32) rDs[t] = 256.0f / (Dp[0][t] + Dp[1][t] + Dp[2][t] + Dp[3][t]);
    __syncthreads();
    {   // V2[bh][c][k0+kk] = V[k0+kk][c] * rDs[kk]
        int kk = t >> 3, c = t & 7;
        float v = (float)Vt[((long)bh * LL + k0 + kk) * 8 + c];
        V2[((long)bh * 8 + c) * LL + k0 + kk] = (_Float16)(v * rDs[kk]);
    }
}

// ---------------------------------------------------------------------------
// Kernel 3 (AV + Wo, occupancy-preserving): block = (32-q tile, bh); the 4
// waves are the 4 k-splits of 576 (R0's per-wave work EXACTLY: 32q x 576k,
// same MFMA/exp2/barrier cadence).  All 2304 k in-block -> LDS-reduce the 4
// wave partials (8c x 32q), apply per-head Wo slice, atomicAdd: 8 producers
// per out element, 2.36M atomics (~6us; R7's 9.4M cost ~25us, R8's occupancy
// collapse cost ~12us -- this keeps R0's 1152-block shape and 15KB LDS).
// grid (72, 16), block 256.
// ---------------------------------------------------------------------------
__global__ __launch_bounds__(256, 4) void k_av_out(
    const _Float16* __restrict__ Qt, const _Float16* __restrict__ Kt,
    const _Float16* __restrict__ V2, const float* __restrict__ Wo,
    float* __restrict__ out)
{
    __shared__ _Float16 lK[4][2][64][4];   // 4KB: per-wave d-half-split K seg
    __shared__ _Float16 lV[4][8][72];      // 4.5KB: per-wave V2 seg (pad +8)
    __shared__ float    WoS[64][9];        // 2.25KB: WoS[co][c] = Wo[co][h*8+c]
    __shared__ float    Osp[4][8][33];     // 4.2KB: wave partials (pad +1)
    const int t    = threadIdx.x;
    const int qb   = blockIdx.x;           // 0..71: q-tile of 32
    const int bh   = blockIdx.y;           // 0..15
    const int b = bh >> 3, h = bh & 7;
    const int lane = t & 63, w = t >> 6;   // wave w owns k in [576w, 576w+576)
    const int half = lane >> 5, l31 = lane & 31;
    const int cl   = l31 & 7;

    // stage Wo slice for this head: 512 floats, h*8 offset is 32B-aligned
    if (t < 128) {
        int co = t >> 1, c4 = (t & 1) * 4;
        float4 v = *(const float4*)&Wo[co * 64 + h * 8 + c4];
        WoS[co][c4 + 0] = v.x; WoS[co][c4 + 1] = v.y;
        WoS[co][c4 + 2] = v.z; WoS[co][c4 + 3] = v.w;
    }

    // fixed B operand: this block's 32 q-cols (same for all 4 waves)
    half4_t qB = *(const half4_t*)(Qt + ((long)bh * LL + qb * 32 + l31) * 8 + half * 4);

    // staging map: thread t loads for wave seg sw = t>>6
    const int sw = t >> 6, sr = t & 63;            // K row within seg
    const int vc = (t & 63) >> 3, vj = t & 7;      // V2: c row, j8 group
    const _Float16* kbg = Kt + ((long)bh * LL + 576 * sw) * 8;
    const _Float16* vbg = V2 + ((long)bh * 8 + vc) * LL + 576 * sw + vj * 8;

    float4 preK = *(const float4*)(kbg + (long)sr * 8);
    float4 preV = *(const float4*)(vbg);

    float16_t O = {};
    for (int it = 0; it < 9; ++it) {       // 9 x 64k per wave
        __syncthreads();
        *(float2*)&lK[sw][0][sr][0] = make_float2(preK.x, preK.y);   // d 0..3
        *(float2*)&lK[sw][1][sr][0] = make_float2(preK.z, preK.w);   // d 4..7
        *(float4*)&lV[sw][vc][vj * 8] = preV;
        __syncthreads();
        if (it + 1 < 9) {
            preK = *(const float4*)(kbg + (long)(64 * (it + 1) + sr) * 8);
            preV = *(const float4*)(vbg + 64 * (it + 1));
        }
        #pragma unroll
        for (int T = 0; T < 2; ++T) {
            const int kb = T * 32;
            half4_t kA = *(const half4_t*)&lK[w][half][kb + l31][0];
            float16_t S = __builtin_amdgcn_mfma_f32_32x32x8f16(kA, qB, (float16_t){}, 0, 0, 0);
            #pragma unroll
            for (int g = 0; g < 4; ++g) {
                half2_t p0 = pk_f16(__builtin_amdgcn_exp2f(S[4 * g + 0]),
                                    __builtin_amdgcn_exp2f(S[4 * g + 1]));
                half2_t p1 = pk_f16(__builtin_amdgcn_exp2f(S[4 * g + 2]),
                                    __builtin_amdgcn_exp2f(S[4 * g + 3]));
                half4_t pB = __builtin_shufflevector(p0, p1, 0, 1, 2, 3);
                half4_t vA = *(const half4_t*)&lV[w][cl][kb + g * 8 + half * 4];
                O = __builtin_amdgcn_mfma_f32_32x32x8f16(vA, pB, O, 0, 0, 0);
            }
        }
    }

    // wave partials: rows c = r + 4*half (c<8 in regs 0..3), col q = l31
    #pragma unroll
    for (int r = 0; r < 4; ++r)
        Osp[w][r + 4 * half][l31] = O[r] * (1.0f / 256.0f);
    __syncthreads();

    // epilogue: thread = (q = t&31, cog = t>>5); sum k-split partials, apply
    // Wo slice (broadcast reads), 8 coalesced atomics (2x128B segs per instr)
    {
        const int q = t & 31, cog = t >> 5;
        float o8[8];
        #pragma unroll
        for (int c = 0; c < 8; ++c)
            o8[c] = Osp[0][c][q] + Osp[1][c][q] + Osp[2][c][q] + Osp[3][c][q];
        float* ob = out + ((long)b * CCH + cog * 8) * LL + qb * 32 + q;
        #pragma unroll
        for (int j = 0; j < 8; ++j) {
            float a = 0.f;
            #pragma unroll
            for (int c = 0; c < 8; ++c)
                a = fmaf(WoS[cog * 8 + j][c], o8[c], a);
            atomicAdd(ob + (long)j * LL, a);
        }
    }
}

// ---------------------------------------------------------------------------
extern "C" void kernel_launch(void* const* d_in, const int* in_sizes, int n_in,
                              void* d_out, int out_size, void* d_ws, size_t ws_size,
                              hipStream_t stream)
{
    const float* x  = (const float*)d_in[0];
    const float* Wq = (const float*)d_in[1];
    const float* bq = (const float*)d_in[2];
    const float* Wk = (const float*)d_in[3];
    const float* bk = (const float*)d_in[4];
    const float* Wv = (const float*)d_in[5];
    const float* bv = (const float*)d_in[6];
    const float* Wo = (const float*)d_in[7];
    const float* bo = (const float*)d_in[8];

    float* out  = (float*)d_out;          // [2][64][2304]
    float* qout = out + 294912;           // second tuple output: scaled q

    // ws: 4 f16 buffers (576KB ea) = 2.25 MB
    _Float16* Qt = (_Float16*)d_ws;       // [16][2304][8] f16, * log2e*d^-0.5
    _Float16* Kt = Qt + 294912;           // [16][2304][8] f16
    _Float16* Vt = Kt + 294912;           // [16][2304][8] f16 (raw V)
    _Float16* V2 = Vt + 294912;           // [16][8][2304] f16 = V^T * 256/D

    k_qkv   <<<dim3(72, 2, 3), 256, 0, stream>>>(x, Wq, bq, Wk, bk, Wv, bv, bo,
                                                 qout, out, Qt, Kt, Vt);
    k_denom <<<dim3(72, 16),   256, 0, stream>>>(Qt, Kt, Vt, V2);
    k_av_out<<<dim3(72, 16),   256, 0, stream>>>(Qt, Kt, V2, Wo, out);
}